// Round 8
// baseline (313.965 us; speedup 1.0000x reference)
//
#include <hip/hip_runtime.h>
#include <hip/hip_bf16.h>

#define B_SZ   8
#define S_LEN  4096
#define D_K    128
#define KB     64      // keys per step
#define PT_STR 72      // P scratch row stride (shorts)

typedef short  short8  __attribute__((ext_vector_type(8)));
typedef float  floatx4 __attribute__((ext_vector_type(4)));

#define EXP2F(x) exp2f(x)

__device__ __forceinline__ unsigned bfround(float x) {
  unsigned u = __builtin_bit_cast(unsigned, x);
  return (u + 0x7fffu + ((u >> 16) & 1u)) >> 16;
}
__device__ __forceinline__ unsigned bfpack2(float a, float b) {
  return bfround(a) | (bfround(b) << 16);
}

// ======================= fused pre-pass (R7-verified) =======================
// blocks [0,2048): K fp32 -> bf16 copy ; [2048,3072): V -> bf16 transpose [b][d][s]

__global__ __launch_bounds__(256)
void prepass(const float* __restrict__ K, const float* __restrict__ V,
             unsigned short* __restrict__ Kb, unsigned short* __restrict__ Vt) {
  __shared__ float tile[64][65];
  const int bid = blockIdx.x;
  const int t   = threadIdx.x;

  if (bid < 2048) {
    const size_t idx = ((size_t)bid * 256 + t) * 8;
    float4 f0 = *(const float4*)(K + idx);
    float4 f1 = *(const float4*)(K + idx + 4);
    uint4 u;
    u.x = bfpack2(f0.x, f0.y);
    u.y = bfpack2(f0.z, f0.w);
    u.z = bfpack2(f1.x, f1.y);
    u.w = bfpack2(f1.z, f1.w);
    *(uint4*)(Kb + idx) = u;
  } else {
    const int vb  = bid - 2048;
    const int b   = vb >> 7;
    const int rem = vb & 127;
    const int kt  = (rem >> 1) * 64;
    const int dt  = (rem & 1) * 64;
    {
      const int c  = (t & 15) * 4;
      const int r0 = t >> 4;
#pragma unroll
      for (int rr = 0; rr < 4; ++rr) {
        const int r = r0 + rr * 16;
        float4 f = *(const float4*)(V + (size_t)(b * S_LEN + kt + r) * D_K + dt + c);
        tile[r][c]     = f.x;
        tile[r][c + 1] = f.y;
        tile[r][c + 2] = f.z;
        tile[r][c + 3] = f.w;
      }
    }
    __syncthreads();
    {
      const int d  = t >> 2;
      const int k0 = (t & 3) * 16;
#pragma unroll
      for (int j = 0; j < 16; j += 8) {
        uint4 u;
        u.x = bfpack2(tile[k0 + j + 0][d], tile[k0 + j + 1][d]);
        u.y = bfpack2(tile[k0 + j + 2][d], tile[k0 + j + 3][d]);
        u.z = bfpack2(tile[k0 + j + 4][d], tile[k0 + j + 5][d]);
        u.w = bfpack2(tile[k0 + j + 6][d], tile[k0 + j + 7][d]);
        *(uint4*)(Vt + (size_t)(b * D_K + dt + d) * S_LEN + kt + k0 + j) = u;
      }
    }
  }
}

// ======================= worker: intra-block key-split =======================
// 512 blocks x 4 waves, all co-resident (2 blocks/CU -> 2 waves/SIMD).
// Each block handles two 32-q tiles (qj = 127-h, then h) -> uniform ~66 steps.
// Within a tile, wave w takes key-steps s === w (mod 4) with private online
// softmax; one LDS combine per tile merges the 4 partials (no global partials,
// no device fences). K/V frags load global->register (R7: no staging, no
// barrier in the K-loop).

__global__ __launch_bounds__(256, 2)
void attn_worker(const float* __restrict__ Q, const unsigned short* __restrict__ Kb,
                 const unsigned short* __restrict__ Vt, float* __restrict__ O) {
  __shared__ __align__(16) float Cmb[3 * 4096];          // 48 KB: waves 1-3 acc
  __shared__ __align__(16) float Cml[4][2][2][16];       // 1 KB: [w][sub][m/l][q]
  __shared__ __align__(16) short Plds[4 * 16 * PT_STR];  // 9216 B: P roundtrip

  const int tid  = threadIdx.x;
  const int w    = tid >> 6;
  const int lane = tid & 63;
  const int l15  = lane & 15;
  const int quad = lane >> 4;

  const int p = blockIdx.x;
  const int b = p & 7;
  const int h = p >> 3;          // 0..63

  const float CSC = 0.12752041f; // log2(e)/sqrt(128)

  // per-lane invariant fragment bases
  const unsigned short* kl = Kb + (size_t)b * S_LEN * D_K + (size_t)l15 * D_K + quad * 8;
  const unsigned short* vl = Vt + (size_t)b * D_K * S_LEN + (size_t)l15 * S_LEN + quad * 8;

  for (int tsel = 0; tsel < 2; ++tsel) {
    const int qj     = tsel ? h : (127 - h);
    const int q0     = qj * 32;
    const int nsteps = (qj >> 1) + 1;

    // ---- Q fragments (B-operand: n=l15=query, k=quad*8+j=d) ----
    short8 bq[2][4];
    int qg[2];
#pragma unroll
    for (int sub = 0; sub < 2; ++sub) {
      qg[sub] = q0 + sub * 16 + l15;
      const float* qrow = Q + (size_t)(b * S_LEN + qg[sub]) * D_K + quad * 8;
#pragma unroll
      for (int kd = 0; kd < 4; ++kd) {
        float4 f0 = *(const float4*)(qrow + kd * 32);
        float4 f1 = *(const float4*)(qrow + kd * 32 + 4);
        union { short8 s; unsigned u[4]; } t;
        t.u[0] = bfpack2(f0.x, f0.y);
        t.u[1] = bfpack2(f0.z, f0.w);
        t.u[2] = bfpack2(f1.x, f1.y);
        t.u[3] = bfpack2(f1.z, f1.w);
        bq[sub][kd] = t.s;
      }
    }

    floatx4 acc[2][8];
#pragma unroll
    for (int sub = 0; sub < 2; ++sub)
#pragma unroll
      for (int nc = 0; nc < 8; ++nc) acc[sub][nc] = (floatx4){0.f, 0.f, 0.f, 0.f};
    float m_run[2] = {-1e30f, -1e30f}, l_run[2] = {0.f, 0.f};

    // ---- preload this wave's first step ----
    short8 ak[4][4];
    if (w < nsteps) {
      const int kt0 = w * KB;
#pragma unroll
      for (int kf = 0; kf < 4; ++kf)
#pragma unroll
        for (int kd = 0; kd < 4; ++kd)
          ak[kf][kd] = *(const short8*)(kl + (size_t)(kt0 + kf * 16) * D_K + kd * 32);
    }

    for (int s = w; s < nsteps; s += 4) {
      const int kt = s * KB;

      // ---- issue V B-frag loads (used after softmax; latency covered) ----
      short8 bv[8][2];
#pragma unroll
      for (int nc = 0; nc < 8; ++nc)
#pragma unroll
        for (int c = 0; c < 2; ++c)
          bv[nc][c] = *(const short8*)(vl + (size_t)(nc * 16) * S_LEN + kt + c * 32);

      // ---- S^T = K*Q^T (C: col=l15=query, row=quad*4+reg=key) ----
      floatx4 st[2][4];
#pragma unroll
      for (int kf = 0; kf < 4; ++kf) {
        floatx4 c0 = (floatx4){0.f, 0.f, 0.f, 0.f};
        floatx4 c1 = (floatx4){0.f, 0.f, 0.f, 0.f};
#pragma unroll
        for (int kd = 0; kd < 4; ++kd) {
          c0 = __builtin_amdgcn_mfma_f32_16x16x32_bf16(ak[kf][kd], bq[0][kd], c0, 0, 0, 0);
          c1 = __builtin_amdgcn_mfma_f32_16x16x32_bf16(ak[kf][kd], bq[1][kd], c1, 0, 0, 0);
        }
        st[0][kf] = c0;
        st[1][kf] = c1;
      }

      // ---- prefetch this wave's next step (s+4) ----
      if (s + 4 < nsteps) {
        const int kt2 = (s + 4) * KB;
#pragma unroll
        for (int kf = 0; kf < 4; ++kf)
#pragma unroll
          for (int kd = 0; kd < 4; ++kd)
            ak[kf][kd] = *(const short8*)(kl + (size_t)(kt2 + kf * 16) * D_K + kd * 32);
      }

      // ---- causal mask (diagonal step only) ----
      if (s == nsteps - 1) {
#pragma unroll
        for (int sub = 0; sub < 2; ++sub)
#pragma unroll
          for (int kf = 0; kf < 4; ++kf)
#pragma unroll
            for (int rr = 0; rr < 4; ++rr) {
              int key = kt + kf * 16 + quad * 4 + rr;
              if (key > qg[sub]) st[sub][kf][rr] = -1e30f;
            }
      }

      // ---- online softmax + P roundtrip + rescale ----
      short8 pa[2][2];
#pragma unroll
      for (int sub = 0; sub < 2; ++sub) {
        float mx = st[sub][0][0];
#pragma unroll
        for (int kf = 0; kf < 4; ++kf)
#pragma unroll
          for (int rr = 0; rr < 4; ++rr) mx = fmaxf(mx, st[sub][kf][rr]);
        mx = fmaxf(mx, __shfl_xor(mx, 16, 64));
        mx = fmaxf(mx, __shfl_xor(mx, 32, 64));
        const float m_new = fmaxf(m_run[sub], mx);
        const float alpha = EXP2F((m_run[sub] - m_new) * CSC);

        float pp[4][4];
        float tsum = 0.f;
#pragma unroll
        for (int kf = 0; kf < 4; ++kf)
#pragma unroll
          for (int rr = 0; rr < 4; ++rr) {
            pp[kf][rr] = EXP2F((st[sub][kf][rr] - m_new) * CSC);
            tsum += pp[kf][rr];
          }
        tsum += __shfl_xor(tsum, 16, 64);
        tsum += __shfl_xor(tsum, 32, 64);
        l_run[sub] = l_run[sub] * alpha + tsum;
        m_run[sub] = m_new;

#pragma unroll
        for (int rr = 0; rr < 4; ++rr) {
          const float ar = __shfl(alpha, quad * 4 + rr, 64);
#pragma unroll
          for (int nc = 0; nc < 8; ++nc) acc[sub][nc][rr] *= ar;
        }

        short* pw = &Plds[(w * 16 + l15) * PT_STR];
#pragma unroll
        for (int kf = 0; kf < 4; ++kf) {
          uint2 u;
          u.x = bfpack2(pp[kf][0], pp[kf][1]);
          u.y = bfpack2(pp[kf][2], pp[kf][3]);
          *(uint2*)(&pw[kf * 16 + quad * 4]) = u;
        }
        __asm__ __volatile__("" ::: "memory");
        pa[sub][0] = *(const short8*)(&pw[quad * 8]);
        pa[sub][1] = *(const short8*)(&pw[32 + quad * 8]);
        __asm__ __volatile__("" ::: "memory");
      }

      // ---- O += P*V with register B-frags ----
#pragma unroll
      for (int nc = 0; nc < 8; ++nc) {
        acc[0][nc] = __builtin_amdgcn_mfma_f32_16x16x32_bf16(pa[0][0], bv[nc][0], acc[0][nc], 0, 0, 0);
        acc[0][nc] = __builtin_amdgcn_mfma_f32_16x16x32_bf16(pa[0][1], bv[nc][1], acc[0][nc], 0, 0, 0);
        acc[1][nc] = __builtin_amdgcn_mfma_f32_16x16x32_bf16(pa[1][0], bv[nc][0], acc[1][nc], 0, 0, 0);
        acc[1][nc] = __builtin_amdgcn_mfma_f32_16x16x32_bf16(pa[1][1], bv[nc][1], acc[1][nc], 0, 0, 0);
      }
    }

    // ---- intra-block combine of the 4 key-split partials ----
    // m/l live per (sub, l15=query); acc rows are query quad*4+rr, col l15 = d.
    if (quad == 0) {
#pragma unroll
      for (int sub = 0; sub < 2; ++sub) {
        Cml[w][sub][0][l15] = m_run[sub];
        Cml[w][sub][1][l15] = l_run[sub];
      }
    }
    if (w > 0) {
      float4* cb = (float4*)(Cmb + (size_t)(w - 1) * 4096);
#pragma unroll
      for (int sub = 0; sub < 2; ++sub)
#pragma unroll
        for (int nc = 0; nc < 8; ++nc) {
          floatx4 a = acc[sub][nc];
          cb[(sub * 8 + nc) * 64 + lane] = make_float4(a[0], a[1], a[2], a[3]);
        }
    }
    __syncthreads();

    if (w == 0) {
#pragma unroll
      for (int sub = 0; sub < 2; ++sub) {
#pragma unroll
        for (int rr = 0; rr < 4; ++rr) {
          const int qq = quad * 4 + rr;    // query index within subtile
          float m0 = Cml[0][sub][0][qq], m1 = Cml[1][sub][0][qq];
          float m2 = Cml[2][sub][0][qq], m3 = Cml[3][sub][0][qq];
          const float M = fmaxf(fmaxf(m0, m1), fmaxf(m2, m3));
          const float w0 = EXP2F((m0 - M) * CSC);
          const float w1 = EXP2F((m1 - M) * CSC);
          const float w2 = EXP2F((m2 - M) * CSC);
          const float w3 = EXP2F((m3 - M) * CSC);
          const float L = w0 * Cml[0][sub][1][qq] + w1 * Cml[1][sub][1][qq]
                        + w2 * Cml[2][sub][1][qq] + w3 * Cml[3][sub][1][qq];
          const float inv = 1.0f / L;
          const int qout = q0 + sub * 16 + qq;
          float* op = O + (size_t)(b * S_LEN + qout) * D_K + l15;
#pragma unroll
          for (int nc = 0; nc < 8; ++nc) {
            const int c = sub * 8 + nc;
            float4 p1 = ((const float4*)(Cmb))[c * 64 + lane];
            float4 p2 = ((const float4*)(Cmb + 4096))[c * 64 + lane];
            float4 p3 = ((const float4*)(Cmb + 8192))[c * 64 + lane];
            const float* e1 = (const float*)&p1;
            const float* e2 = (const float*)&p2;
            const float* e3 = (const float*)&p3;
            float v = w0 * acc[sub][nc][rr] + w1 * e1[rr] + w2 * e2[rr] + w3 * e3[rr];
            op[nc * 16] = v * inv;
          }
        }
      }
    }
    __syncthreads();   // protect Cmb/Cml reuse for the second tile
  }
}

// ======================= fallback (R2 kernel, known-good) =======================

#define KT_STR 136
#define VT_STR 72

__global__ __launch_bounds__(256, 2)
void attn_fwd_fb(const float* __restrict__ Q, const float* __restrict__ K,
                 const float* __restrict__ V, float* __restrict__ O) {
  __shared__ __align__(16) short Klds[KB * KT_STR];
  __shared__ __align__(16) short Vtlds[D_K * VT_STR];
  __shared__ __align__(16) short Plds2[4 * 16 * PT_STR];

  const int tid  = threadIdx.x;
  const int lane = tid & 63;
  const int w    = tid >> 6;
  const int l15  = lane & 15;
  const int quad = lane >> 4;

  const int bid = blockIdx.x;
  const int b   = bid & 7;
  const int qi  = 63 - (bid >> 3);
  const int q0  = qi * 64;

  const float CSC = 0.12752041f;

  const int    qg   = q0 + w * 16 + l15;
  const float* qrow = Q + (size_t)(b * S_LEN + qg) * D_K + quad * 8;
  short8 bq[4];
#pragma unroll
  for (int kd = 0; kd < 4; ++kd) {
    float4 f0 = *(const float4*)(qrow + kd * 32);
    float4 f1 = *(const float4*)(qrow + kd * 32 + 4);
    union { short8 s; unsigned u[4]; } t;
    t.u[0] = bfpack2(f0.x, f0.y);
    t.u[1] = bfpack2(f0.z, f0.w);
    t.u[2] = bfpack2(f1.x, f1.y);
    t.u[3] = bfpack2(f1.z, f1.w);
    bq[kd] = t.s;
  }

  floatx4 acc[8];
#pragma unroll
  for (int nc = 0; nc < 8; ++nc) acc[nc] = (floatx4){0.f, 0.f, 0.f, 0.f};
  float m_run = -1e30f, l_run = 0.f;

  const int d4 = tid & 31;
  const int kq = tid >> 5;
  const int nsteps = qi + 1;

  for (int s = 0; s < nsteps; ++s) {
    const int kt = s * KB;
#pragma unroll
    for (int r2 = 0; r2 < 2; ++r2) {
      const int row = r2 * 32 + kq * 4;
      const float* kp = K + (size_t)(b * S_LEN + kt + row) * D_K + d4 * 4;
      const float* vp = V + (size_t)(b * S_LEN + kt + row) * D_K + d4 * 4;
      float4 fk[4], fv[4];
#pragma unroll
      for (int i = 0; i < 4; ++i) {
        fk[i] = *(const float4*)(kp + i * D_K);
        fv[i] = *(const float4*)(vp + i * D_K);
      }
#pragma unroll
      for (int i = 0; i < 4; ++i) {
        uint2 u;
        u.x = bfpack2(fk[i].x, fk[i].y);
        u.y = bfpack2(fk[i].z, fk[i].w);
        *(uint2*)(&Klds[(row + i) * KT_STR + d4 * 4]) = u;
      }
#pragma unroll
      for (int c = 0; c < 4; ++c) {
        float e0 = ((const float*)&fv[0])[c];
        float e1 = ((const float*)&fv[1])[c];
        float e2 = ((const float*)&fv[2])[c];
        float e3 = ((const float*)&fv[3])[c];
        uint2 u;
        u.x = bfpack2(e0, e1);
        u.y = bfpack2(e2, e3);
        *(uint2*)(&Vtlds[(d4 * 4 + c) * VT_STR + row]) = u;
      }
    }
    __syncthreads();

    floatx4 st[4];
#pragma unroll
    for (int kf = 0; kf < 4; ++kf) {
      floatx4 c = (floatx4){0.f, 0.f, 0.f, 0.f};
#pragma unroll
      for (int kd = 0; kd < 4; ++kd) {
        short8 a = *(const short8*)(&Klds[(kf * 16 + l15) * KT_STR + kd * 32 + quad * 8]);
        c = __builtin_amdgcn_mfma_f32_16x16x32_bf16(a, bq[kd], c, 0, 0, 0);
      }
      st[kf] = c;
    }

    if (s == nsteps - 1) {
#pragma unroll
      for (int kf = 0; kf < 4; ++kf)
#pragma unroll
        for (int rr = 0; rr < 4; ++rr) {
          int key = kt + kf * 16 + quad * 4 + rr;
          if (key > qg) st[kf][rr] = -1e30f;
        }
    }

    float mx = st[0][0];
#pragma unroll
    for (int kf = 0; kf < 4; ++kf)
#pragma unroll
      for (int rr = 0; rr < 4; ++rr) mx = fmaxf(mx, st[kf][rr]);
    mx = fmaxf(mx, __shfl_xor(mx, 16, 64));
    mx = fmaxf(mx, __shfl_xor(mx, 32, 64));
    const float m_new = fmaxf(m_run, mx);
    const float alpha = EXP2F((m_run - m_new) * CSC);

    float pp[4][4];
    float tsum = 0.f;
#pragma unroll
    for (int kf = 0; kf < 4; ++kf)
#pragma unroll
      for (int rr = 0; rr < 4; ++rr) {
        pp[kf][rr] = EXP2F((st[kf][rr] - m_new) * CSC);
        tsum += pp[kf][rr];
      }
    tsum += __shfl_xor(tsum, 16, 64);
    tsum += __shfl_xor(tsum, 32, 64);
    l_run = l_run * alpha + tsum;
    m_run = m_new;

#pragma unroll
    for (int rr = 0; rr < 4; ++rr) {
      const float ar = __shfl(alpha, quad * 4 + rr, 64);
#pragma unroll
      for (int nc = 0; nc < 8; ++nc) acc[nc][rr] *= ar;
    }

    short* pw = &Plds2[(w * 16 + l15) * PT_STR];
#pragma unroll
    for (int kf = 0; kf < 4; ++kf) {
      uint2 u;
      u.x = bfpack2(pp[kf][0], pp[kf][1]);
      u.y = bfpack2(pp[kf][2], pp[kf][3]);
      *(uint2*)(&pw[kf * 16 + quad * 4]) = u;
    }
    __asm__ __volatile__("" ::: "memory");
    short8 pa0 = *(const short8*)(&pw[quad * 8]);
    short8 pa1 = *(const short8*)(&pw[32 + quad * 8]);

#pragma unroll
    for (int nc = 0; nc < 8; ++nc) {
      short8 bv0 = *(const short8*)(&Vtlds[(nc * 16 + l15) * VT_STR + quad * 8]);
      acc[nc] = __builtin_amdgcn_mfma_f32_16x16x32_bf16(pa0, bv0, acc[nc], 0, 0, 0);
      short8 bv1 = *(const short8*)(&Vtlds[(nc * 16 + l15) * VT_STR + 32 + quad * 8]);
      acc[nc] = __builtin_amdgcn_mfma_f32_16x16x32_bf16(pa1, bv1, acc[nc], 0, 0, 0);
    }
    __syncthreads();
  }

#pragma unroll
  for (int rr = 0; rr < 4; ++rr) {
    const float lr  = __shfl(l_run, quad * 4 + rr, 64);
    const float inv = 1.0f / lr;
    const int qout  = q0 + w * 16 + quad * 4 + rr;
    float* op = O + (size_t)(b * S_LEN + qout) * D_K + l15;
#pragma unroll
    for (int nc = 0; nc < 8; ++nc) op[nc * 16] = acc[nc][rr] * inv;
  }
}

// ======================= launch =======================

extern "C" void kernel_launch(void* const* d_in, const int* in_sizes, int n_in,
                              void* d_out, int out_size, void* d_ws, size_t ws_size,
                              hipStream_t stream) {
  const float* Q = (const float*)d_in[0];
  const float* K = (const float*)d_in[1];
  const float* V = (const float*)d_in[2];
  float* O = (float*)d_out;

  const size_t elems = (size_t)B_SZ * S_LEN * D_K;   // 4.19M

  const size_t off_kb = 0;
  const size_t off_vt = off_kb + elems * 2;
  const size_t need   = off_vt + elems * 2;          // ~16.8 MB

  if (ws_size >= need) {
    char* ws = (char*)d_ws;
    unsigned short* Kb = (unsigned short*)(ws + off_kb);
    unsigned short* Vt = (unsigned short*)(ws + off_vt);

    prepass<<<dim3(3072), dim3(256), 0, stream>>>(K, V, Kb, Vt);
    attn_worker<<<dim3(512), dim3(256), 0, stream>>>(Q, Kb, Vt, O);
  } else {
    attn_fwd_fb<<<dim3(512), dim3(256), 0, stream>>>(Q, K, V, O);
  }
}